// Round 5
// baseline (402.330 us; speedup 1.0000x reference)
//
#include <hip/hip_runtime.h>
#include <hip/hip_fp16.h>

#define NN 50000      // nodes (fits in 16 bits: col packed as ushort)
#define NE 800000     // edges
#define DF 64         // features
#define DH 32         // half feature dim (split so gather table fits 4MiB XCD L2)
#define MM 11         // (a,b) tuples
#define OUT_K 4       // DEPTH+1 output planes
#define PAD 16        // row slabs padded to multiple of PAD
#define SLAB_CAP (NE + (PAD - 1) * NN + 64)
#define GRID_BIG 2048

typedef unsigned int uivec4 __attribute__((ext_vector_type(4)));

__device__ __forceinline__ float bf2f(unsigned short u) {
    union { unsigned int i; float f; } v; v.i = ((unsigned int)u) << 16; return v.f;
}
__device__ __forceinline__ unsigned short f2bf(float f) {
    union { float f; unsigned int i; } v; v.f = f;
    unsigned int u = v.i + 0x7FFFu + ((v.i >> 16) & 1u);
    return (unsigned short)(u >> 16);
}

// ---------------- CSR build ----------------

// deg + per-edge rank (atomic's old value) with the independent x->bf16 cast
// fused in (cast hides under atomic-return latency). Cast writes SPLIT halves:
// xa = features 0-31, xb = features 32-63, each [NN][32] bf16 = 3.2 MB.
__global__ __launch_bounds__(256) void k_deg_cast(
        const int* __restrict__ row, int* __restrict__ deg,
        unsigned short* __restrict__ rank,
        const float* __restrict__ x,
        unsigned short* __restrict__ xa, unsigned short* __restrict__ xb) {
    int stride = gridDim.x * blockDim.x;
    int t0 = blockIdx.x * blockDim.x + threadIdx.x;
    for (int e = t0; e < NE; e += stride) {
        int r = row[e];
        rank[e] = (unsigned short)atomicAdd(&deg[r], 1);
    }
    const float4* xf = (const float4*)x;
    for (int j = t0; j < (NN * DF) / 8; j += stride) {
        int node = j >> 3, grp = j & 7;          // 8 groups of 8 floats per node
        float4 f0 = xf[2 * j];
        float4 f1 = xf[2 * j + 1];
        uint4 o;
        o.x = (unsigned int)f2bf(f0.x) | ((unsigned int)f2bf(f0.y) << 16);
        o.y = (unsigned int)f2bf(f0.z) | ((unsigned int)f2bf(f0.w) << 16);
        o.z = (unsigned int)f2bf(f1.x) | ((unsigned int)f2bf(f1.y) << 16);
        o.w = (unsigned int)f2bf(f1.z) | ((unsigned int)f2bf(f1.w) << 16);
        unsigned short* dst = (grp < 4) ? xa : xb;
        ((uint4*)(dst + node * DH + (grp & 3) * 8))[0] = o;
    }
}

// slab alloc: 1024-thread blocks, two-level (wave shfl + LDS) scan,
// ONE atomic per block (49 total). gamma parallelized over m on wave 0 of block 0.
__global__ __launch_bounds__(1024) void k_alloc(
        const int* __restrict__ deg, int* __restrict__ counter,
        int* __restrict__ rowstart, float* __restrict__ dinv,
        const float* __restrict__ alphas, const float* __restrict__ w,
        const float* __restrict__ a_arr, const float* __restrict__ b_arr,
        float* __restrict__ gamma) {
    __shared__ int wtot[16];
    __shared__ int blockbase;
    int i = blockIdx.x * 1024 + threadIdx.x;
    int wave = threadIdx.x >> 6;
    int lane = threadIdx.x & 63;

    int d = (i < NN) ? deg[i] : 0;
    int dp = (d + PAD - 1) & ~(PAD - 1);
    int v = dp;
    #pragma unroll
    for (int off = 1; off < 64; off <<= 1) {
        int t = __shfl_up(v, off, 64);
        if (lane >= off) v += t;
    }
    if (lane == 63) wtot[wave] = v;
    __syncthreads();
    if (wave == 0) {
        int t = (lane < 16) ? wtot[lane] : 0;
        #pragma unroll
        for (int off = 1; off < 16; off <<= 1) {
            int u = __shfl_up(t, off, 64);
            if (lane >= off) t += u;
        }
        if (lane == 15) blockbase = atomicAdd(counter, t);  // block total
        if (lane < 16) wtot[lane] = t;                      // inclusive scan
    }
    __syncthreads();
    int base = blockbase + (wave ? wtot[wave - 1] : 0);
    if (i < NN) {
        rowstart[i] = base + v - dp;
        dinv[i] = 1.0f / sqrtf((float)(d == 0 ? 1 : d));
    }

    // gamma[k][j] = sum_m w_m c_{k,m,j}: one m per lane, shuffle-reduce.
    if (blockIdx.x == 0 && wave == 0) {
        float g[OUT_K][OUT_K];
        #pragma unroll
        for (int k = 0; k < OUT_K; ++k)
            #pragma unroll
            for (int j = 0; j < OUT_K; ++j) g[k][j] = 0.f;
        if (lane < MM) {
            int m = lane;
            float a = a_arr[m], b = b_arr[m], wm = w[m];
            float c[OUT_K][OUT_K];
            #pragma unroll
            for (int k = 0; k < OUT_K; ++k)
                #pragma unroll
                for (int j = 0; j < OUT_K; ++j) c[k][j] = 0.f;
            c[0][0] = 1.f;
            float al0 = alphas[m];
            c[1][0] = al0 * 0.5f * (a - b);        // l=-1, r=1
            c[1][1] = al0 * 0.5f * (a + b + 2.f);
            #pragma unroll
            for (int L = 2; L <= 3; ++L) {
                float Lf = (float)L;
                float alL = alphas[(L - 1) * MM + m];
                float alm = alphas[(L - 2) * MM + m];
                float ab = a + b;
                float t2L = 2.f * Lf + ab;
                float coef_l = 2.f * Lf * (Lf + ab) * (t2L - 2.f);
                float inv = 1.f / coef_l;
                float t1 = alL * ((t2L - 1.f) * t2L * (t2L - 2.f)) * inv;
                float t2 = alL * ((t2L - 1.f) * (a * a - b * b)) * inv;
                float t3 = alL * alm * (2.f * (Lf - 1.f + a) * (Lf - 1.f + b) * t2L) * inv;
                #pragma unroll
                for (int j = 0; j < OUT_K; ++j) {
                    float ps = (j > 0) ? c[L - 1][j - 1] : 0.f;
                    c[L][j] = t1 * ps - t2 * c[L - 1][j] - t3 * c[L - 2][j];
                }
            }
            #pragma unroll
            for (int k = 0; k < OUT_K; ++k)
                #pragma unroll
                for (int j = 0; j < OUT_K; ++j) g[k][j] = wm * c[k][j];
        }
        #pragma unroll
        for (int k = 0; k < OUT_K; ++k)
            #pragma unroll
            for (int j = 0; j < OUT_K; ++j) {
                float s = g[k][j];
                #pragma unroll
                for (int off = 32; off >= 1; off >>= 1) s += __shfl_down(s, off, 64);
                if (lane == 0) gamma[k * OUT_K + j] = s;
            }
    }
}

// fill: atomic-free (pos = rowstart + precomputed rank), grid-stride.
// Edge weight stores only ea*dinv[col]; dinv[row] is row-constant, applied in SpMM.
__global__ __launch_bounds__(256) void k_fill(
        const int* __restrict__ row, const int* __restrict__ col,
        const float* __restrict__ ea, const float* __restrict__ dinv,
        const int* __restrict__ rowstart,
        const unsigned short* __restrict__ rank,
        unsigned int* __restrict__ ecv) {
    int stride = gridDim.x * blockDim.x;
    for (int e = blockIdx.x * blockDim.x + threadIdx.x; e < NE; e += stride) {
        int r = row[e], c = col[e];
        int pos = rowstart[r] + (int)rank[e];
        float v = ea[e] * dinv[c];
        unsigned short hb = __half_as_ushort(__float2half(v));
        ecv[pos] = (unsigned int)(unsigned short)c | ((unsigned int)hb << 16);
    }
}

// ------------- SpMM, split-feature: wave = (row, half), 2 edges/gather -------------
// lanes 0-31 process even edges, lanes 32-63 odd edges, same 32 features.
// Gather table is one 3.2 MB half -> fully L2-resident per XCD.
// Returns the full row sum (all 64 lanes) for feature (lane&31) of this half.
__device__ __forceinline__ float spmm_row_h(const unsigned int* __restrict__ ecv,
                                            int s, int n,
                                            const unsigned short* __restrict__ xin,
                                            int sub, int f) {
    float acc = 0.f;
    for (int i = s; i < s + n; i += PAD) {
        const uivec4* p = (const uivec4*)(ecv + i);
        uivec4 q0 = __builtin_nontemporal_load(p);
        uivec4 q1 = __builtin_nontemporal_load(p + 1);
        uivec4 q2 = __builtin_nontemporal_load(p + 2);
        uivec4 q3 = __builtin_nontemporal_load(p + 3);
        unsigned int rec[PAD] = {q0.x, q0.y, q0.z, q0.w, q1.x, q1.y, q1.z, q1.w,
                                 q2.x, q2.y, q2.z, q2.w, q3.x, q3.y, q3.z, q3.w};
        unsigned short g[PAD / 2];
        #pragma unroll
        for (int j = 0; j < PAD / 2; ++j) {
            int c = (int)(rec[2 * j + sub] & 0xFFFFu);
            g[j] = xin[c * DH + f];
        }
        #pragma unroll
        for (int j = 0; j < PAD / 2; ++j)
            acc += __half2float(__ushort_as_half((unsigned short)(rec[2 * j + sub] >> 16)))
                   * bf2f(g[j]);
    }
    acc += __shfl_xor(acc, 32, 64);   // combine even-edge + odd-edge partial sums
    return acc;
}

__global__ __launch_bounds__(256, 8) void k_spmm(
    const int* __restrict__ rowstart, const int* __restrict__ deg,
    const float* __restrict__ dinv,
    const unsigned int* __restrict__ ecv,
    const unsigned short* __restrict__ xa, const unsigned short* __restrict__ xb,
    unsigned short* __restrict__ oa, unsigned short* __restrict__ ob) {
    int wid = (blockIdx.x * blockDim.x + threadIdx.x) >> 6;
    if (wid >= 2 * NN) return;
    int lane = threadIdx.x & 63;
    int half = (wid >= NN);
    int r = wid - half * NN;
    int sub = lane >> 5, f = lane & 31;
    const unsigned short* xin = half ? xb : xa;
    int s = rowstart[r];
    int n = (deg[r] + PAD - 1) & ~(PAD - 1);
    float acc = spmm_row_h(ecv, s, n, xin, sub, f) * dinv[r];
    if (lane < 32) (half ? ob : oa)[r * DH + f] = f2bf(acc);
}

// third SpMM with the output combine fused (y3 never hits memory);
// v1/v2 read from the bf16 half-tables of previous layers.
__global__ __launch_bounds__(256, 8) void k_spmm_comb(
    const int* __restrict__ rowstart, const int* __restrict__ deg,
    const float* __restrict__ dinv,
    const unsigned int* __restrict__ ecv,
    const unsigned short* __restrict__ x2a, const unsigned short* __restrict__ x2b,
    const float* __restrict__ x,
    const unsigned short* __restrict__ x1a, const unsigned short* __restrict__ x1b,
    const float* __restrict__ gamma, float* __restrict__ out) {
    int wid = (blockIdx.x * blockDim.x + threadIdx.x) >> 6;
    if (wid >= 2 * NN) return;
    int lane = threadIdx.x & 63;
    int half = (wid >= NN);
    int r = wid - half * NN;
    int sub = lane >> 5, f = lane & 31;
    const unsigned short* xin = half ? x2b : x2a;
    int s = rowstart[r];
    int n = (deg[r] + PAD - 1) & ~(PAD - 1);
    float v3 = spmm_row_h(ecv, s, n, xin, sub, f) * dinv[r];
    if (lane < 32) {
        float v0 = x[r * DF + half * DH + f];
        float v1 = bf2f((half ? x1b : x1a)[r * DH + f]);
        float v2 = bf2f((half ? x2b : x2a)[r * DH + f]);
        #pragma unroll
        for (int k = 0; k < OUT_K; ++k) {
            float o = gamma[k * OUT_K + 0] * v0 + gamma[k * OUT_K + 1] * v1 +
                      gamma[k * OUT_K + 2] * v2 + gamma[k * OUT_K + 3] * v3;
            out[(r * OUT_K + k) * DF + half * DH + f] = o;
        }
    }
}

// ---------------- launch ----------------

extern "C" void kernel_launch(void* const* d_in, const int* in_sizes, int n_in,
                              void* d_out, int out_size, void* d_ws, size_t ws_size,
                              hipStream_t stream) {
    const float* x      = (const float*)d_in[0];
    const int*   ei     = (const int*)d_in[1];
    const float* ea     = (const float*)d_in[2];
    const float* alphas = (const float*)d_in[3];
    const float* w      = (const float*)d_in[4];
    const float* a_arr  = (const float*)d_in[5];
    const float* b_arr  = (const float*)d_in[6];
    float* out = (float*)d_out;
    const int* row = ei;
    const int* col = ei + NE;

    char* ws = (char*)d_ws;
    size_t off = 0;
    auto alloc = [&](size_t bytes) {
        void* p = ws + off;
        off = (off + bytes + 255) & ~(size_t)255;
        return p;
    };
    // deg/counter then ecv are contiguous so ONE memset zeroes all
    // (ecv pad slots must be 0: col=0, fp16 val=0).
    int* deg      = (int*)alloc((size_t)(NN + 1) * sizeof(int));
    int* counter  = deg + NN;
    unsigned int* ecv = (unsigned int*)alloc((size_t)SLAB_CAP * sizeof(unsigned int));
    size_t zero_end = off;
    int* rowstart = (int*)alloc((size_t)NN * sizeof(int));
    float* dinv   = (float*)alloc((size_t)NN * sizeof(float));
    unsigned short* rank = (unsigned short*)alloc((size_t)NE * sizeof(unsigned short));
    unsigned short* x0a = (unsigned short*)alloc((size_t)NN * DH * sizeof(unsigned short));
    unsigned short* x0b = (unsigned short*)alloc((size_t)NN * DH * sizeof(unsigned short));
    unsigned short* x1a = (unsigned short*)alloc((size_t)NN * DH * sizeof(unsigned short));
    unsigned short* x1b = (unsigned short*)alloc((size_t)NN * DH * sizeof(unsigned short));
    unsigned short* x2a = (unsigned short*)alloc((size_t)NN * DH * sizeof(unsigned short));
    unsigned short* x2b = (unsigned short*)alloc((size_t)NN * DH * sizeof(unsigned short));
    float* gamma = (float*)alloc((size_t)OUT_K * OUT_K * sizeof(float));

    (void)hipMemsetAsync(deg, 0, zero_end, stream);

    k_deg_cast<<<GRID_BIG, 256, 0, stream>>>(row, deg, rank, x, x0a, x0b);
    k_alloc<<<(NN + 1023) / 1024, 1024, 0, stream>>>(deg, counter, rowstart, dinv,
                                                     alphas, w, a_arr, b_arr, gamma);
    k_fill<<<GRID_BIG, 256, 0, stream>>>(row, col, ea, dinv, rowstart, rank, ecv);

    int blocks = (2 * NN + 3) / 4;  // one wave per (row, half)
    k_spmm<<<blocks, 256, 0, stream>>>(rowstart, deg, dinv, ecv, x0a, x0b, x1a, x1b);
    k_spmm<<<blocks, 256, 0, stream>>>(rowstart, deg, dinv, ecv, x1a, x1b, x2a, x2b);
    k_spmm_comb<<<blocks, 256, 0, stream>>>(rowstart, deg, dinv, ecv, x2a, x2b,
                                            x, x1a, x1b, gamma, out);
}

// Round 6
// 214.343 us; speedup vs baseline: 1.8770x; 1.8770x over previous
//
#include <hip/hip_runtime.h>
#include <hip/hip_fp16.h>

#define NN 50000      // nodes (fits in 16 bits: col packed as ushort)
#define NE 800000     // edges
#define DF 64         // features
#define MM 11         // (a,b) tuples
#define OUT_K 4       // DEPTH+1 output planes
#define PAD 16        // row slabs padded to multiple of PAD
// pair-max padding: each row pair padded to 2*max -> bounded by 2*sum
#define SLAB_CAP (2 * (NE + (PAD - 1) * NN) + 128)

typedef unsigned int uivec4 __attribute__((ext_vector_type(4)));

__device__ __forceinline__ float bf2f(unsigned short u) {
    union { unsigned int i; float f; } v; v.i = ((unsigned int)u) << 16; return v.f;
}
__device__ __forceinline__ unsigned short f2bf(float f) {
    union { float f; unsigned int i; } v; v.f = f;
    unsigned int u = v.i + 0x7FFFu + ((v.i >> 16) & 1u);
    return (unsigned short)(u >> 16);
}

// ---------------- CSR build ----------------

// deg AND per-edge rank within its row (the atomic's old value — free sort key)
__global__ void k_deg(const int* __restrict__ row, int* __restrict__ deg,
                      unsigned short* __restrict__ rank) {
    int e = blockIdx.x * blockDim.x + threadIdx.x;
    if (e < NE) {
        int r = row[e];
        rank[e] = (unsigned short)atomicAdd(&deg[r], 1);
    }
}

// slab alloc: 1024-thread blocks, two-level (wave shfl + LDS) scan,
// ONE atomic per block. Row pairs (2i,2i+1) padded to a COMMON length
// m = max(pad(deg_2i), pad(deg_2i+1)) so the dual-row SpMM wave has zero
// divergence; m is recoverable as rowstart[2i+1]-rowstart[2i].
// gamma parallelized over m on wave 0 of block 0.
__global__ __launch_bounds__(1024) void k_alloc(
        const int* __restrict__ deg, int* __restrict__ counter,
        int* __restrict__ rowstart, float* __restrict__ dinv,
        const float* __restrict__ alphas, const float* __restrict__ w,
        const float* __restrict__ a_arr, const float* __restrict__ b_arr,
        float* __restrict__ gamma) {
    __shared__ int wtot[16];
    __shared__ int blockbase;
    int i = blockIdx.x * 1024 + threadIdx.x;
    int wave = threadIdx.x >> 6;
    int lane = threadIdx.x & 63;

    int d = (i < NN) ? deg[i] : 0;
    int dp = (d + PAD - 1) & ~(PAD - 1);
    int dpo = __shfl_xor(dp, 1, 64);      // pair partner's padded length
    int mp = max(dp, dpo);                // common pair length
    int v = mp;
    #pragma unroll
    for (int off = 1; off < 64; off <<= 1) {
        int t = __shfl_up(v, off, 64);
        if (lane >= off) v += t;
    }
    if (lane == 63) wtot[wave] = v;
    __syncthreads();
    if (wave == 0) {
        int t = (lane < 16) ? wtot[lane] : 0;
        #pragma unroll
        for (int off = 1; off < 16; off <<= 1) {
            int u = __shfl_up(t, off, 64);
            if (lane >= off) t += u;
        }
        if (lane == 15) blockbase = atomicAdd(counter, t);  // block total
        if (lane < 16) wtot[lane] = t;                      // inclusive scan
    }
    __syncthreads();
    int base = blockbase + (wave ? wtot[wave - 1] : 0);
    if (i < NN) {
        rowstart[i] = base + v - mp;      // even row: pair base; odd: base+m
        dinv[i] = 1.0f / sqrtf((float)(d == 0 ? 1 : d));
    }

    // gamma[k][j] = sum_m w_m c_{k,m,j}: one m per lane, shuffle-reduce.
    if (blockIdx.x == 0 && wave == 0) {
        float g[OUT_K][OUT_K];
        #pragma unroll
        for (int k = 0; k < OUT_K; ++k)
            #pragma unroll
            for (int j = 0; j < OUT_K; ++j) g[k][j] = 0.f;
        if (lane < MM) {
            int m = lane;
            float a = a_arr[m], b = b_arr[m], wm = w[m];
            float c[OUT_K][OUT_K];
            #pragma unroll
            for (int k = 0; k < OUT_K; ++k)
                #pragma unroll
                for (int j = 0; j < OUT_K; ++j) c[k][j] = 0.f;
            c[0][0] = 1.f;
            float al0 = alphas[m];
            c[1][0] = al0 * 0.5f * (a - b);        // l=-1, r=1
            c[1][1] = al0 * 0.5f * (a + b + 2.f);
            #pragma unroll
            for (int L = 2; L <= 3; ++L) {
                float Lf = (float)L;
                float alL = alphas[(L - 1) * MM + m];
                float alm = alphas[(L - 2) * MM + m];
                float ab = a + b;
                float t2L = 2.f * Lf + ab;
                float coef_l = 2.f * Lf * (Lf + ab) * (t2L - 2.f);
                float inv = 1.f / coef_l;
                float t1 = alL * ((t2L - 1.f) * t2L * (t2L - 2.f)) * inv;
                float t2 = alL * ((t2L - 1.f) * (a * a - b * b)) * inv;
                float t3 = alL * alm * (2.f * (Lf - 1.f + a) * (Lf - 1.f + b) * t2L) * inv;
                #pragma unroll
                for (int j = 0; j < OUT_K; ++j) {
                    float ps = (j > 0) ? c[L - 1][j - 1] : 0.f;
                    c[L][j] = t1 * ps - t2 * c[L - 1][j] - t3 * c[L - 2][j];
                }
            }
            #pragma unroll
            for (int k = 0; k < OUT_K; ++k)
                #pragma unroll
                for (int j = 0; j < OUT_K; ++j) g[k][j] = wm * c[k][j];
        }
        #pragma unroll
        for (int k = 0; k < OUT_K; ++k)
            #pragma unroll
            for (int j = 0; j < OUT_K; ++j) {
                float s = g[k][j];
                #pragma unroll
                for (int off = 32; off >= 1; off >>= 1) s += __shfl_down(s, off, 64);
                if (lane == 0) gamma[k * OUT_K + j] = s;
            }
    }
}

// fill (atomic-free: pos = rowstart + precomputed rank) + vectorized bf16 cast of x.
// Record: low16 = col, high16 = bf16(ea*dinv[col]) — decode is a single AND.
// dinv[row] is row-constant, applied in SpMM.
__global__ void k_fill_cast(const int* __restrict__ row, const int* __restrict__ col,
                            const float* __restrict__ ea, const float* __restrict__ dinv,
                            const int* __restrict__ rowstart,
                            const unsigned short* __restrict__ rank,
                            unsigned int* __restrict__ ecv,
                            const float* __restrict__ x, unsigned short* __restrict__ xb) {
    int t = blockIdx.x * blockDim.x + threadIdx.x;
    if (t < NE) {
        int r = row[t], c = col[t];
        int pos = rowstart[r] + (int)rank[t];
        float v = ea[t] * dinv[c];
        ecv[pos] = (unsigned int)(unsigned short)c | ((unsigned int)f2bf(v) << 16);
    } else {
        int j = t - NE;
        if (j < (NN * DF) / 8) {
            const float4* xf = (const float4*)x;
            float4 f0 = xf[2 * j];
            float4 f1 = xf[2 * j + 1];
            uint4 o;
            o.x = (unsigned int)f2bf(f0.x) | ((unsigned int)f2bf(f0.y) << 16);
            o.y = (unsigned int)f2bf(f0.z) | ((unsigned int)f2bf(f0.w) << 16);
            o.z = (unsigned int)f2bf(f1.x) | ((unsigned int)f2bf(f1.y) << 16);
            o.w = (unsigned int)f2bf(f1.z) | ((unsigned int)f2bf(f1.w) << 16);
            ((uint4*)xb)[j] = o;
        }
    }
}

// ------ SpMM: wave = row PAIR; lanes 0-31 row 2w, lanes 32-63 row 2w+1 ------
// Each lane covers 2 features (one uint gather = 2 bf16). Decode serves 2 rows
// and 2 features -> ~4.1 VALU issues/edge vs 7.3 in the 1-row/1-feat version.
__device__ __forceinline__ void spmm_pair(const unsigned int* __restrict__ ecv,
                                          int s, int m,
                                          const unsigned short* __restrict__ xin,
                                          int fp, float& a0, float& a1) {
    for (int i = 0; i < m; i += PAD) {
        const uivec4* p = (const uivec4*)(ecv + s + i);
        uivec4 q0 = __builtin_nontemporal_load(p);
        uivec4 q1 = __builtin_nontemporal_load(p + 1);
        uivec4 q2 = __builtin_nontemporal_load(p + 2);
        uivec4 q3 = __builtin_nontemporal_load(p + 3);
        unsigned int rec[PAD] = {q0.x, q0.y, q0.z, q0.w, q1.x, q1.y, q1.z, q1.w,
                                 q2.x, q2.y, q2.z, q2.w, q3.x, q3.y, q3.z, q3.w};
        unsigned int g[PAD];
        #pragma unroll
        for (int j = 0; j < PAD; ++j)
            g[j] = *(const unsigned int*)(xin + (rec[j] & 0xFFFFu) * DF + 2 * fp);
        #pragma unroll
        for (int j = 0; j < PAD; ++j) {
            float wf = __uint_as_float(rec[j] & 0xFFFF0000u);  // bf16 weight
            a0 = fmaf(wf, __uint_as_float(g[j] << 16), a0);
            a1 = fmaf(wf, __uint_as_float(g[j] & 0xFFFF0000u), a1);
        }
    }
}

__global__ __launch_bounds__(256, 8) void k_spmm(
    const int* __restrict__ rowstart, const float* __restrict__ dinv,
    const unsigned int* __restrict__ ecv, const unsigned short* __restrict__ xin,
    unsigned short* __restrict__ bout) {
    int wv = (blockIdx.x * blockDim.x + threadIdx.x) >> 6;  // pair index
    if (wv >= NN / 2) return;
    int lane = threadIdx.x & 63;
    int h = lane >> 5, fp = lane & 31;
    int r = 2 * wv + h;
    int s = rowstart[r];
    int so = __shfl_xor(s, 32, 64);
    int m = h ? (s - so) : (so - s);     // common pair length
    float a0 = 0.f, a1 = 0.f;
    spmm_pair(ecv, s, m, xin, fp, a0, a1);
    float dv = dinv[r];
    a0 *= dv; a1 *= dv;
    unsigned int o = (unsigned int)f2bf(a0) | ((unsigned int)f2bf(a1) << 16);
    *(unsigned int*)(bout + r * DF + 2 * fp) = o;
}

// third SpMM with the output combine fused (y3 never hits memory);
// v1/v2 read back from the bf16 tables (f32 y1/y2 never exist).
__global__ __launch_bounds__(256, 8) void k_spmm_comb(
    const int* __restrict__ rowstart, const float* __restrict__ dinv,
    const unsigned int* __restrict__ ecv, const unsigned short* __restrict__ xin,
    const float* __restrict__ x, const unsigned short* __restrict__ xb1,
    const float* __restrict__ gamma, float* __restrict__ out) {
    int wv = (blockIdx.x * blockDim.x + threadIdx.x) >> 6;
    if (wv >= NN / 2) return;
    int lane = threadIdx.x & 63;
    int h = lane >> 5, fp = lane & 31;
    int r = 2 * wv + h;
    int s = rowstart[r];
    int so = __shfl_xor(s, 32, 64);
    int m = h ? (s - so) : (so - s);
    float a0 = 0.f, a1 = 0.f;
    spmm_pair(ecv, s, m, xin, fp, a0, a1);
    float dv = dinv[r];
    a0 *= dv; a1 *= dv;                   // v3 pair
    int base = r * DF + 2 * fp;
    float2 v0 = *(const float2*)(x + base);
    unsigned int u1 = *(const unsigned int*)(xb1 + base);
    unsigned int u2 = *(const unsigned int*)(xin + base);   // xin == xb2 table
    float v1l = __uint_as_float(u1 << 16);
    float v1h = __uint_as_float(u1 & 0xFFFF0000u);
    float v2l = __uint_as_float(u2 << 16);
    float v2h = __uint_as_float(u2 & 0xFFFF0000u);
    float gm[OUT_K * OUT_K];
    #pragma unroll
    for (int t = 0; t < OUT_K * OUT_K; ++t) gm[t] = gamma[t];
    #pragma unroll
    for (int k = 0; k < OUT_K; ++k) {
        float2 o;
        o.x = gm[k * OUT_K + 0] * v0.x + gm[k * OUT_K + 1] * v1l +
              gm[k * OUT_K + 2] * v2l + gm[k * OUT_K + 3] * a0;
        o.y = gm[k * OUT_K + 0] * v0.y + gm[k * OUT_K + 1] * v1h +
              gm[k * OUT_K + 2] * v2h + gm[k * OUT_K + 3] * a1;
        *(float2*)(out + (r * OUT_K + k) * DF + 2 * fp) = o;
    }
}

// ---------------- launch ----------------

extern "C" void kernel_launch(void* const* d_in, const int* in_sizes, int n_in,
                              void* d_out, int out_size, void* d_ws, size_t ws_size,
                              hipStream_t stream) {
    const float* x      = (const float*)d_in[0];
    const int*   ei     = (const int*)d_in[1];
    const float* ea     = (const float*)d_in[2];
    const float* alphas = (const float*)d_in[3];
    const float* w      = (const float*)d_in[4];
    const float* a_arr  = (const float*)d_in[5];
    const float* b_arr  = (const float*)d_in[6];
    float* out = (float*)d_out;
    const int* row = ei;
    const int* col = ei + NE;

    char* ws = (char*)d_ws;
    size_t off = 0;
    auto alloc = [&](size_t bytes) {
        void* p = ws + off;
        off = (off + bytes + 255) & ~(size_t)255;
        return p;
    };
    // deg/counter then ecv are contiguous so ONE memset zeroes all
    // (ecv pad slots must be 0: col=0, bf16 weight=+0).
    int* deg      = (int*)alloc((size_t)(NN + 1) * sizeof(int));
    int* counter  = deg + NN;
    unsigned int* ecv = (unsigned int*)alloc((size_t)SLAB_CAP * sizeof(unsigned int));
    size_t zero_end = off;
    int* rowstart = (int*)alloc((size_t)NN * sizeof(int));
    float* dinv   = (float*)alloc((size_t)NN * sizeof(float));
    unsigned short* rank = (unsigned short*)alloc((size_t)NE * sizeof(unsigned short));
    unsigned short* xb0 = (unsigned short*)alloc((size_t)NN * DF * sizeof(unsigned short));
    unsigned short* xb1 = (unsigned short*)alloc((size_t)NN * DF * sizeof(unsigned short));
    unsigned short* xb2 = (unsigned short*)alloc((size_t)NN * DF * sizeof(unsigned short));
    float* gamma = (float*)alloc((size_t)OUT_K * OUT_K * sizeof(float));

    (void)hipMemsetAsync(deg, 0, zero_end, stream);

    k_deg<<<(NE + 255) / 256, 256, 0, stream>>>(row, deg, rank);
    k_alloc<<<(NN + 1023) / 1024, 1024, 0, stream>>>(deg, counter, rowstart, dinv,
                                                     alphas, w, a_arr, b_arr, gamma);
    k_fill_cast<<<(NE + (NN * DF) / 8 + 255) / 256, 256, 0, stream>>>(
        row, col, ea, dinv, rowstart, rank, ecv, x, xb0);

    int blocks = (NN / 2 + 3) / 4;  // one wave per row PAIR, 4 pairs/block
    k_spmm<<<blocks, 256, 0, stream>>>(rowstart, dinv, ecv, xb0, xb1);
    k_spmm<<<blocks, 256, 0, stream>>>(rowstart, dinv, ecv, xb1, xb2);
    k_spmm_comb<<<blocks, 256, 0, stream>>>(rowstart, dinv, ecv, xb2, x, xb1,
                                            gamma, out);
}